// Round 6
// baseline (107.165 us; speedup 1.0000x reference)
//
#include <hip/hip_runtime.h>
#include <hip/hip_bf16.h>

// EmbeddingLoss: loss = sum_{i<j} [ same ? mse : max(0,1-mse) ] / (B*(B-1))
// mse_ij = (sq_i + sq_j - 2*gram_ij)/D, gram = E E^T.
// Round 5 (resubmit; prior round hit GPUAcquisitionTimeout):
// R4 main loop unchanged (32x32x16 MFMA, dbuf, counted vmcnt(8)).
// Epilogue rebuilt: 4 coalesced sq/lab vector loads issued BEFORE staging
// (latency hidden under the whole main loop), per-element values obtained
// via __shfl broadcasts -> ZERO global loads after the MFMA loop.

#define BN 8192
#define DK 256
#define NT 64                      // BN/128 tiles per dim
#define NBLK (NT * (NT + 1) / 2)   // 2080 upper-tri tiles = 8*260

typedef __bf16 bf16x8 __attribute__((ext_vector_type(8)));
typedef float f32x16 __attribute__((ext_vector_type(16)));

typedef const __attribute__((address_space(1))) void* gas_vp;
typedef __attribute__((address_space(3))) void* las_vp;

static __device__ __forceinline__ unsigned short f2bf(float f) {
    unsigned u = __builtin_bit_cast(unsigned, f);
    u += 0x7fffu + ((u >> 16) & 1u);          // round-to-nearest-even
    return (unsigned short)(u >> 16);
}

// ---------------- prep: fp32->bf16 (ws) + fp32 row norms (ws), zero out ----
__global__ __launch_bounds__(256) void embl_prep(
    const float* __restrict__ E, unsigned short* __restrict__ Eb,
    float* __restrict__ sq, float* __restrict__ out)
{
    const int lane = threadIdx.x & 63;
    const int wid  = threadIdx.x >> 6;
    const int row  = blockIdx.x * 4 + wid;    // one row per wave
    if (blockIdx.x == 0 && threadIdx.x == 0) *out = 0.0f;
    const float4 v = *(const float4*)(E + row * DK + lane * 4);
    float s = v.x*v.x + v.y*v.y + v.z*v.z + v.w*v.w;
    ushort4 o;
    o.x = f2bf(v.x); o.y = f2bf(v.y); o.z = f2bf(v.z); o.w = f2bf(v.w);
    *(ushort4*)(Eb + row * DK + lane * 4) = o;
    #pragma unroll
    for (int off = 32; off > 0; off >>= 1) s += __shfl_xor(s, off, 64);
    if (lane == 0) sq[row] = s;
}

// ---------------- main: 128x128 gram tile, 4 waves, dbuf pipeline ----------
__global__ __launch_bounds__(256, 2) void embl_gram(
    const unsigned short* __restrict__ Ebu, const float* __restrict__ sq,
    const int* __restrict__ lab, float* __restrict__ out)
{
    __shared__ alignas(16) __bf16 As[2][128 * 64];
    __shared__ alignas(16) __bf16 Bs[2][128 * 64];
    __shared__ float wpart[4];

    // XCD-aware chunked swizzle, bijective: 2080 = 8 * 260
    const int bid = (blockIdx.x & 7) * 260 + (blockIdx.x >> 3);
    // upper-tri decode: bid -> (ti, tj), ti <= tj
    int t = bid, ti = 0, rl = NT;
    while (t >= rl) { t -= rl; --rl; ++ti; }
    const int tj = ti + t;

    const int tid  = threadIdx.x;
    const int lane = tid & 63;
    const int wid  = tid >> 6;
    const int wr   = wid >> 1;          // 0..1 -> 64-row half
    const int wc   = wid & 1;           // 0..1 -> 64-col half

    const int lrow = lane & 31;         // MFMA row-in-frag
    const int lhi  = lane >> 5;         // k-half select
    const int lx   = lane & 7;          // read-side XOR key (== row & 7)

    const char* Ebc = (const char*)Ebu;
    const int arow = ti * 128;
    const int brow = tj * 128;
    const int gi0  = arow + wr * 64;
    const int gj0  = brow + wc * 64;

    // ---- epilogue data: 4 coalesced loads, issued FIRST (oldest vmcnt) ----
    const float sq_i_vec = sq[gi0 + lane];
    const int   lb_i_vec = lab[gi0 + lane];
    const float sq_j_vec = sq[gj0 + lane];
    const int   lb_j_vec = lab[gj0 + lane];
    asm volatile("" :: "v"(sq_i_vec), "v"(lb_i_vec), "v"(sq_j_vec), "v"(lb_j_vec));

    // stage one operand K-tile (128 rows x 64 cols bf16 = 16KB): 4 loads/thr.
    // Linear LDS dest chunk c; global source chunk XOR-swizzled (involution).
#define STAGE(dst, grow, kt)                                                   \
    {                                                                          \
        _Pragma("unroll")                                                      \
        for (int it_ = 0; it_ < 4; ++it_) {                                    \
            const int c_   = it_ * 256 + tid;                                  \
            const int row_ = c_ >> 3;                                          \
            const int sch_ = (c_ & 7) ^ (row_ & 7);                            \
            __builtin_amdgcn_global_load_lds(                                  \
                (gas_vp)(Ebc + (long)((grow) + row_) * 512 + (kt) * 128 + sch_ * 16), \
                (las_vp)((char*)(dst) + c_ * 16), 16, 0, 0);                   \
        }                                                                      \
    }

    // vmcnt-counted tile boundary: wait-N, then raw barrier (no full drain)
#define WAITVM(N)                                                              \
    {                                                                          \
        asm volatile("s_waitcnt vmcnt(" #N ")" ::: "memory");                  \
        __builtin_amdgcn_sched_barrier(0);                                     \
        __builtin_amdgcn_s_barrier();                                          \
        __builtin_amdgcn_sched_barrier(0);                                     \
    }

    // swizzled fragment reads (rows stride 128B; chunk ^= row&7 == lane&7)
#define LDA(buf, m, kc)                                                        \
    (*(const bf16x8*)((const char*)&As[buf][0] +                               \
        (wr * 64 + (m) * 32 + lrow) * 128 + ((((kc) * 2) + lhi) ^ lx) * 16))
#define LDB(buf, n, kc)                                                        \
    (*(const bf16x8*)((const char*)&Bs[buf][0] +                               \
        (wc * 64 + (n) * 32 + lrow) * 128 + ((((kc) * 2) + lhi) ^ lx) * 16))

#define MFMA32(a, b, c) __builtin_amdgcn_mfma_f32_32x32x16_bf16(a, b, c, 0, 0, 0)

#define TILE(buf)                                                              \
    {                                                                          \
        bf16x8 a_[2][4], b_[2][4];                                             \
        _Pragma("unroll")                                                      \
        for (int kc = 0; kc < 4; ++kc) {                                       \
            a_[0][kc] = LDA(buf, 0, kc);                                       \
            a_[1][kc] = LDA(buf, 1, kc);                                       \
            b_[0][kc] = LDB(buf, 0, kc);                                       \
            b_[1][kc] = LDB(buf, 1, kc);                                       \
        }                                                                      \
        __builtin_amdgcn_s_setprio(1);                                         \
        _Pragma("unroll")                                                      \
        for (int kc = 0; kc < 4; ++kc) {                                       \
            acc[0][0] = MFMA32(a_[0][kc], b_[0][kc], acc[0][0]);               \
            acc[0][1] = MFMA32(a_[0][kc], b_[1][kc], acc[0][1]);               \
            acc[1][0] = MFMA32(a_[1][kc], b_[0][kc], acc[1][0]);               \
            acc[1][1] = MFMA32(a_[1][kc], b_[1][kc], acc[1][1]);               \
        }                                                                      \
        __builtin_amdgcn_s_setprio(0);                                         \
        __builtin_amdgcn_sched_barrier(0);                                     \
        __builtin_amdgcn_s_barrier();   /* all waves done reading buf */       \
        __builtin_amdgcn_sched_barrier(0);                                     \
    }

    f32x16 acc[2][2] = {};

    // prologue: stage K-tiles 0 and 1 (16 staging loads + 4 scalar preloads)
    STAGE(As[0], arow, 0); STAGE(Bs[0], brow, 0);
    STAGE(As[1], arow, 1); STAGE(Bs[1], brow, 1);
    WAITVM(8);                          // t0 landed (scalar preloads retired first)
    TILE(0);
    STAGE(As[0], arow, 2); STAGE(Bs[0], brow, 2);
    WAITVM(8);                          // t1 landed (t2 in flight)
    TILE(1);
    STAGE(As[1], arow, 3); STAGE(Bs[1], brow, 3);
    WAITVM(8);                          // t2 landed (t3 in flight)
    TILE(0);
    WAITVM(0);                          // t3 landed
    TILE(1);

    // ---- epilogue: C/D layout col=lane&31, row=(reg&3)+8*(reg>>2)+4*lhi ----
    // All per-element sq/lab values via __shfl broadcast from the 4 preloads.
    float lsum = 0.0f;

    float sqjv[2]; int ljv[2], jv[2];
    #pragma unroll
    for (int n_ = 0; n_ < 2; ++n_) {
        const int jl = n_ * 32 + lrow;
        jv[n_]   = gj0 + jl;
        sqjv[n_] = __shfl(sq_j_vec, jl, 64);
        ljv[n_]  = __shfl(lb_j_vec, jl, 64);
    }

#define EPI(MASKED)                                                            \
    {                                                                          \
        _Pragma("unroll")                                                      \
        for (int m_ = 0; m_ < 2; ++m_)                                         \
        _Pragma("unroll")                                                      \
        for (int rq = 0; rq < 4; ++rq)                                         \
        _Pragma("unroll")                                                      \
        for (int rr = 0; rr < 4; ++rr) {                                       \
            const int il = m_ * 32 + 4 * lhi + rq * 8 + rr;                    \
            const float sqi_ = __shfl(sq_i_vec, il, 64);                       \
            const int   li_  = __shfl(lb_i_vec, il, 64);                       \
            const int   i_   = gi0 + il;                                       \
            _Pragma("unroll")                                                  \
            for (int n_ = 0; n_ < 2; ++n_) {                                   \
                const float mse_ =                                             \
                    (sqi_ + sqjv[n_] - 2.0f * acc[m_][n_][rq * 4 + rr]) *      \
                    (1.0f / 256.0f);                                           \
                float v_ = (li_ == ljv[n_]) ? mse_                             \
                                            : fmaxf(0.0f, 1.0f - mse_);       \
                if (MASKED && i_ >= jv[n_]) v_ = 0.0f;                         \
                lsum += v_;                                                    \
            }                                                                  \
        }                                                                      \
    }

    if (ti == tj) { EPI(1) } else { EPI(0) }

    #pragma unroll
    for (int off = 32; off > 0; off >>= 1) lsum += __shfl_xor(lsum, off, 64);
    if (lane == 0) wpart[wid] = lsum;
    __syncthreads();
    if (tid == 0) {
        const float scale = 1.0f / ((float)BN * (float)(BN - 1));
        atomicAdd(out, (wpart[0] + wpart[1] + wpart[2] + wpart[3]) * scale);
    }
}

extern "C" void kernel_launch(void* const* d_in, const int* in_sizes, int n_in,
                              void* d_out, int out_size, void* d_ws, size_t ws_size,
                              hipStream_t stream) {
    const float* E   = (const float*)d_in[0];
    const int*   lab = (const int*)d_in[1];
    float*       out = (float*)d_out;

    unsigned short* Eb = (unsigned short*)d_ws;                       // 4 MiB
    float*          sq = (float*)((char*)d_ws + (size_t)BN * DK * 2); // 32 KiB

    embl_prep<<<BN / 4, 256, 0, stream>>>(E, Eb, sq, out);
    embl_gram<<<NBLK, 256, 0, stream>>>(Eb, sq, lab, out);
}

// Round 7
// 97.426 us; speedup vs baseline: 1.1000x; 1.1000x over previous
//
#include <hip/hip_runtime.h>
#include <hip/hip_bf16.h>

// EmbeddingLoss: loss = sum_{i<j} [ same ? mse : max(0,1-mse) ] / (B*(B-1))
// mse_ij = (sq_i + sq_j - 2*gram_ij)/D, gram = E E^T.
// Round 7: m201-style 256x256 tile, 8 waves (2Mx4N), 16 phases
// (4 K-tiles x 4 C-quadrant phases), dual barrier per phase, counted vmcnt,
// T2 XOR swizzle, T5 setprio. Halves staging traffic vs 128^2 and adds
// per-phase MFMA/ds_read/stage interleave (the proven 1563-TF structure).

#define BN 8192
#define DK 256
#define NT 32                      // BN/256 tiles per dim
#define NBLK (NT * (NT + 1) / 2)   // 528 upper-tri tiles = 8*66

typedef __bf16 bf16x8 __attribute__((ext_vector_type(8)));
typedef float f32x4 __attribute__((ext_vector_type(4)));

typedef const __attribute__((address_space(1))) void* gas_vp;
typedef __attribute__((address_space(3))) void* las_vp;

static __device__ __forceinline__ unsigned short f2bf(float f) {
    unsigned u = __builtin_bit_cast(unsigned, f);
    u += 0x7fffu + ((u >> 16) & 1u);          // round-to-nearest-even
    return (unsigned short)(u >> 16);
}

// ---------------- prep: fp32->bf16 (ws) + fp32 row norms (ws), zero out ----
__global__ __launch_bounds__(256) void embl_prep(
    const float* __restrict__ E, unsigned short* __restrict__ Eb,
    float* __restrict__ sq, float* __restrict__ out)
{
    const int lane = threadIdx.x & 63;
    const int wid  = threadIdx.x >> 6;
    const int row  = blockIdx.x * 4 + wid;    // one row per wave
    if (blockIdx.x == 0 && threadIdx.x == 0) *out = 0.0f;
    const float4 v = *(const float4*)(E + row * DK + lane * 4);
    float s = v.x*v.x + v.y*v.y + v.z*v.z + v.w*v.w;
    ushort4 o;
    o.x = f2bf(v.x); o.y = f2bf(v.y); o.z = f2bf(v.z); o.w = f2bf(v.w);
    *(ushort4*)(Eb + row * DK + lane * 4) = o;
    #pragma unroll
    for (int off = 32; off > 0; off >>= 1) s += __shfl_xor(s, off, 64);
    if (lane == 0) sq[row] = s;
}

// ---------------- main: 256x256 gram tile, 8 waves, 16-phase pipeline ------
__global__ __launch_bounds__(512, 2) void embl_gram(
    const unsigned short* __restrict__ Ebu, const float* __restrict__ sq,
    const int* __restrict__ lab, float* __restrict__ out)
{
    __shared__ alignas(16) __bf16 As[2][256 * 64];   // [buf][row][64 cols]
    __shared__ alignas(16) __bf16 Bs[2][256 * 64];
    __shared__ float wpart[8];

    // XCD-aware chunked swizzle, bijective: 528 = 8 * 66
    const int bid = (blockIdx.x & 7) * 66 + (blockIdx.x >> 3);
    // upper-tri decode: bid -> (ti, tj), ti <= tj
    int t = bid, ti = 0, rl = NT;
    while (t >= rl) { t -= rl; --rl; ++ti; }
    const int tj = ti + t;

    const int tid  = threadIdx.x;
    const int lane = tid & 63;
    const int wid  = tid >> 6;          // 0..7
    const int wr   = wid >> 2;          // 0..1 -> 128-row half
    const int wc   = wid & 3;           // 0..3 -> 64-col quarter

    const int lcol = lane & 15;         // MFMA frag row index
    const int lk   = lane >> 4;         // 0..3 k-chunk group

    const char* Ebc = (const char*)Ebu;
    const int arow = ti * 256;
    const int brow = tj * 256;

    // stage one operand K-tile (256 rows x 64 cols bf16 = 32KB): 4 loads/thr
    // (512 threads). Linear LDS dest; source chunk XOR-pre-swizzled.
#define STAGE(dst, grow, kt)                                                   \
    {                                                                          \
        _Pragma("unroll")                                                      \
        for (int it_ = 0; it_ < 4; ++it_) {                                    \
            const int c_   = it_ * 512 + tid;   /* 0..2047 */                  \
            const int row_ = c_ >> 3;           /* 0..255  */                  \
            const int sch_ = (c_ & 7) ^ (row_ & 7);                            \
            __builtin_amdgcn_global_load_lds(                                  \
                (gas_vp)(Ebc + (long)((grow) + row_) * 512 + (kt) * 128 + sch_ * 16), \
                (las_vp)((char*)(dst) + c_ * 16), 16, 0, 0);                   \
        }                                                                      \
    }

#define WAITVM(N)                                                              \
    {                                                                          \
        asm volatile("s_waitcnt vmcnt(" #N ")" ::: "memory");                  \
        __builtin_amdgcn_sched_barrier(0);                                     \
        __builtin_amdgcn_s_barrier();                                          \
        __builtin_amdgcn_sched_barrier(0);                                     \
    }

    // swizzled fragment reads: row stride 128B (8 chunks); chunk ^= row&7
#define LDA(buf, m, ks)                                                        \
    (*(const bf16x8*)((const char*)&As[buf][0] +                               \
        (wr * 128 + (m) * 16 + lcol) * 128 +                                   \
        ((((ks) * 4) + lk) ^ ((wr * 128 + (m) * 16 + lcol) & 7)) * 16))
#define LDB(buf, n, ks)                                                        \
    (*(const bf16x8*)((const char*)&Bs[buf][0] +                               \
        (wc * 64 + (n) * 16 + lcol) * 128 +                                    \
        ((((ks) * 4) + lk) ^ ((wc * 64 + (n) * 16 + lcol) & 7)) * 16))

#define MFMA16(a, b, c) __builtin_amdgcn_mfma_f32_16x16x32_bf16(a, b, c, 0, 0, 0)

    // one phase: C-quadrant q (rows 2q,2q+1 of the 8x4 frag grid), all 4 n.
    // 12 ds_read_b128 + optional stage-issue + barrier + 16 MFMA + barrier.
#define PHASE(buf, q, EXTRA)                                                   \
    {                                                                          \
        bf16x8 a0_[2], a1_[2], b_[4][2];                                       \
        _Pragma("unroll")                                                      \
        for (int ks = 0; ks < 2; ++ks) {                                       \
            a0_[ks] = LDA(buf, 2 * (q), ks);                                   \
            a1_[ks] = LDA(buf, 2 * (q) + 1, ks);                               \
            _Pragma("unroll")                                                  \
            for (int n_ = 0; n_ < 4; ++n_) b_[n_][ks] = LDB(buf, n_, ks);      \
        }                                                                      \
        EXTRA                                                                  \
        __builtin_amdgcn_sched_barrier(0);                                     \
        __builtin_amdgcn_s_barrier();                                          \
        __builtin_amdgcn_sched_barrier(0);                                     \
        __builtin_amdgcn_s_setprio(1);                                         \
        _Pragma("unroll")                                                      \
        for (int ks = 0; ks < 2; ++ks)                                         \
        _Pragma("unroll")                                                      \
        for (int n_ = 0; n_ < 4; ++n_) {                                       \
            acc[2 * (q)][n_]     = MFMA16(a0_[ks], b_[n_][ks], acc[2 * (q)][n_]);     \
            acc[2 * (q) + 1][n_] = MFMA16(a1_[ks], b_[n_][ks], acc[2 * (q) + 1][n_]); \
        }                                                                      \
        __builtin_amdgcn_s_setprio(0);                                         \
        __builtin_amdgcn_sched_barrier(0);                                     \
        __builtin_amdgcn_s_barrier();                                          \
        __builtin_amdgcn_sched_barrier(0);                                     \
    }

    f32x4 acc[8][4] = {};

    // prologue: stage K-tiles 0,1 (8 loads/thread outstanding each)
    STAGE(As[0], arow, 0); STAGE(Bs[0], brow, 0);
    STAGE(As[1], arow, 1); STAGE(Bs[1], brow, 1);
    WAITVM(8);                          // t0 landed; t1 in flight

    // K-tile 0 from b0 (t1 landing underneath)
    PHASE(0, 0, ) PHASE(0, 1, ) PHASE(0, 2, ) PHASE(0, 3, )
    WAITVM(0);                          // t1 landed (long since; b0 now free)

    // K-tile 1 from b1; issue t2 -> b0 in first two phases
    PHASE(1, 0, STAGE(As[0], arow, 2)) PHASE(1, 1, STAGE(Bs[0], brow, 2))
    PHASE(1, 2, ) PHASE(1, 3, )
    WAITVM(0);                          // t2 landed (b1 free)

    // K-tile 2 from b0; issue t3 -> b1 in first two phases
    PHASE(0, 0, STAGE(As[1], arow, 3)) PHASE(0, 1, STAGE(Bs[1], brow, 3))
    PHASE(0, 2, ) PHASE(0, 3, )
    WAITVM(0);                          // t3 landed

    // K-tile 3 from b1
    PHASE(1, 0, ) PHASE(1, 1, ) PHASE(1, 2, ) PHASE(1, 3, )

    // ---- epilogue: C/D layout col=lane&15, row=(lane>>4)*4+reg ------------
    const int gi0 = arow + wr * 128;
    const int gj0 = brow + wc * 64;
    float lsum = 0.0f;

#define EPI(MASKED)                                                            \
    {                                                                          \
        float sqj_[4]; int lj_[4], jj_[4];                                     \
        _Pragma("unroll")                                                      \
        for (int n_ = 0; n_ < 4; ++n_) {                                       \
            jj_[n_] = gj0 + n_ * 16 + lcol;                                    \
            sqj_[n_] = sq[jj_[n_]]; lj_[n_] = lab[jj_[n_]];                    \
        }                                                                      \
        _Pragma("unroll")                                                      \
        for (int m_ = 0; m_ < 8; ++m_) {                                       \
            const int ibase = gi0 + m_ * 16 + lk * 4;                          \
            _Pragma("unroll")                                                  \
            for (int r_ = 0; r_ < 4; ++r_) {                                   \
                const int i_ = ibase + r_;                                     \
                const float sqi_ = sq[i_]; const int li_ = lab[i_];            \
                _Pragma("unroll")                                              \
                for (int n_ = 0; n_ < 4; ++n_) {                               \
                    const float mse_ =                                         \
                        (sqi_ + sqj_[n_] - 2.0f * acc[m_][n_][r_]) *           \
                        (1.0f / 256.0f);                                       \
                    float v_ = (li_ == lj_[n_]) ? mse_                         \
                                                : fmaxf(0.0f, 1.0f - mse_);    \
                    if (MASKED && i_ >= jj_[n_]) v_ = 0.0f;                    \
                    lsum += v_;                                                \
                }                                                              \
            }                                                                  \
        }                                                                      \
    }

    if (ti == tj) { EPI(1) } else { EPI(0) }

    #pragma unroll
    for (int off = 32; off > 0; off >>= 1) lsum += __shfl_xor(lsum, off, 64);
    if (lane == 0) wpart[wid] = lsum;
    __syncthreads();
    if (tid == 0) {
        float bs = 0.0f;
        #pragma unroll
        for (int w = 0; w < 8; ++w) bs += wpart[w];
        const float scale = 1.0f / ((float)BN * (float)(BN - 1));
        atomicAdd(out, bs * scale);
    }
}

extern "C" void kernel_launch(void* const* d_in, const int* in_sizes, int n_in,
                              void* d_out, int out_size, void* d_ws, size_t ws_size,
                              hipStream_t stream) {
    const float* E   = (const float*)d_in[0];
    const int*   lab = (const int*)d_in[1];
    float*       out = (float*)d_out;

    unsigned short* Eb = (unsigned short*)d_ws;                       // 4 MiB
    float*          sq = (float*)((char*)d_ws + (size_t)BN * DK * 2); // 32 KiB

    embl_prep<<<BN / 4, 256, 0, stream>>>(E, Eb, sq, out);
    embl_gram<<<NBLK, 512, 0, stream>>>(Eb, sq, lab, out);
}